// Round 3
// baseline (100.488 us; speedup 1.0000x reference)
//
#include <hip/hip_runtime.h>
#include <math.h>

// Problem constants (match reference)
#define T_TOTAL 8192
#define KK      10
#define DMODEL  256
#define BATCH   32
#define D4      (DMODEL/4)                 // 64 float4 per row
#define PE4     (T_TOTAL * D4)             // 524288 float4 in pos_enc
#define PE_BYTES ((size_t)PE4 * 16)        // 8 MiB
#define TOT4    ((size_t)BATCH * PE4)      // 16,777,216 float4 total
#define J_PER_THREAD 8                     // float4 per thread in kernel 2
#define BLK4    (256 * J_PER_THREAD)       // 2048 float4 = 32 KB per block

typedef float f32x4 __attribute__((ext_vector_type(4)));

// ---------------------------------------------------------------------------
// Kernel 1: materialize pos_enc (T_TOTAL x DMODEL) into workspace.
// ---------------------------------------------------------------------------
__global__ __launch_bounds__(256) void gre_pe_build(
    const float* __restrict__ emb,
    const float* __restrict__ mu,
    const float* __restrict__ sigma,
    f32x4* __restrict__ pe4)
{
    const int tid = threadIdx.x;
    const int tl  = tid >> 6;   // 0..3
    const int c   = tid & 63;   // float4 column
    const int t   = blockIdx.x * 4 + tl;

    // stable softmax over K=10 (matches jax.nn.softmax)
    float lp[KK];
    float mx = -INFINITY;
#pragma unroll
    for (int k = 0; k < KK; ++k) {
        const float mk = mu[k];
        const float sk = sigma[k];
        const float a  = (float)t - mk;
        const float v  = -(a * a) / (2.0f * sk + 1e-8f)
                         - 0.5f * __logf(fabsf(sk) + 1e-8f);
        lp[k] = v;
        mx = fmaxf(mx, v);
    }
    float s = 0.0f;
#pragma unroll
    for (int k = 0; k < KK; ++k) {
        lp[k] = __expf(lp[k] - mx);
        s += lp[k];
    }
    const float inv = 1.0f / s;

    const f32x4* __restrict__ emb4 = (const f32x4*)emb;
    f32x4 pe = (f32x4){0.f, 0.f, 0.f, 0.f};
#pragma unroll
    for (int k = 0; k < KK; ++k) {
        pe += (lp[k] * inv) * emb4[k * D4 + c];
    }
    pe4[t * D4 + c] = pe;
}

// ---------------------------------------------------------------------------
// Kernel 2: pure contiguous streaming add. Block owns 32 KB contiguous chunk.
// pe index = flat4 & (PE4-1)  (batch stride is a multiple of PE4).
// ---------------------------------------------------------------------------
__global__ __launch_bounds__(256) void gre_stream_add(
    const f32x4* __restrict__ x4,
    const f32x4* __restrict__ pe4,
    f32x4* __restrict__ o4)
{
    const size_t base = (size_t)blockIdx.x * BLK4 + threadIdx.x;

    // Phase 1: 8 outstanding x loads, 4 KB apart (contiguous 32 KB block span)
    f32x4 v[J_PER_THREAD];
#pragma unroll
    for (int j = 0; j < J_PER_THREAD; ++j)
        v[j] = x4[base + (size_t)j * 256];

    // Phase 2: pe load (L2/L3-hot, 8 MB footprint) + add + nt store
#pragma unroll
    for (int j = 0; j < J_PER_THREAD; ++j) {
        const size_t idx = base + (size_t)j * 256;
        f32x4 r = v[j] + pe4[idx & (size_t)(PE4 - 1)];
        __builtin_nontemporal_store(r, &o4[idx]);
    }
}

// ---------------------------------------------------------------------------
// Fallback (fused, R2 form) in case ws_size < 8 MiB.
// ---------------------------------------------------------------------------
__global__ __launch_bounds__(256) void gre_fused(
    const float* __restrict__ x,
    const float* __restrict__ emb,
    const float* __restrict__ mu,
    const float* __restrict__ sigma,
    float* __restrict__ out)
{
    const int tid = threadIdx.x;
    const int tl  = tid >> 6;
    const int c   = tid & 63;
    const int t   = blockIdx.x * 4 + tl;
    const int b0  = blockIdx.y * 8;

    float lp[KK];
    float mx = -INFINITY;
#pragma unroll
    for (int k = 0; k < KK; ++k) {
        const float mk = mu[k];
        const float sk = sigma[k];
        const float a  = (float)t - mk;
        const float v  = -(a * a) / (2.0f * sk + 1e-8f)
                         - 0.5f * __logf(fabsf(sk) + 1e-8f);
        lp[k] = v;
        mx = fmaxf(mx, v);
    }
    float s = 0.0f;
#pragma unroll
    for (int k = 0; k < KK; ++k) { lp[k] = __expf(lp[k] - mx); s += lp[k]; }
    const float inv = 1.0f / s;

    const f32x4* __restrict__ emb4 = (const f32x4*)emb;
    f32x4 pe = (f32x4){0.f, 0.f, 0.f, 0.f};
#pragma unroll
    for (int k = 0; k < KK; ++k) pe += (lp[k] * inv) * emb4[k * D4 + c];

    const f32x4* __restrict__ x4 = (const f32x4*)x;
    f32x4* __restrict__ o4       = (f32x4*)out;
    const size_t base = (size_t)t * D4 + c + (size_t)b0 * PE4;

    f32x4 v[8];
#pragma unroll
    for (int i = 0; i < 8; ++i) v[i] = x4[base + (size_t)i * PE4];
#pragma unroll
    for (int i = 0; i < 8; ++i) {
        f32x4 r = v[i] + pe;
        __builtin_nontemporal_store(r, &o4[base + (size_t)i * PE4]);
    }
}

extern "C" void kernel_launch(void* const* d_in, const int* in_sizes, int n_in,
                              void* d_out, int out_size, void* d_ws, size_t ws_size,
                              hipStream_t stream) {
    const float* x     = (const float*)d_in[0];
    const float* emb   = (const float*)d_in[1];
    const float* mu    = (const float*)d_in[2];
    const float* sigma = (const float*)d_in[3];
    float* out         = (float*)d_out;

    if (ws_size >= PE_BYTES) {
        f32x4* pe4 = (f32x4*)d_ws;
        gre_pe_build<<<T_TOTAL / 4, 256, 0, stream>>>(emb, mu, sigma, pe4);
        const int blocks = (int)(TOT4 / BLK4);  // 8192
        gre_stream_add<<<blocks, 256, 0, stream>>>(
            (const f32x4*)x, (const f32x4*)pe4, (f32x4*)out);
    } else {
        dim3 grid(T_TOTAL / 4, BATCH / 8);
        gre_fused<<<grid, 256, 0, stream>>>(x, emb, mu, sigma, out);
    }
}

// Round 4
// 81.757 us; speedup vs baseline: 1.2291x; 1.2291x over previous
//
#include <hip/hip_runtime.h>
#include <math.h>

// Problem constants (match reference)
#define T_TOTAL 8192
#define KK      10
#define DMODEL  256
#define BATCH   32
#define D4      (DMODEL/4)                   // 64 float4 per row
#define PE4     (T_TOTAL * D4)               // 524288 float4 per batch
#define TOT4    ((size_t)BATCH * PE4)        // 16,777,216 float4 total
#define JPT     8                            // float4 per thread
#define CHUNK4  (256 * JPT)                  // 2048 float4 = 32 KB per block
#define ROWS_PB 32                           // t-rows per block (CHUNK4 / D4)

typedef float f32x4 __attribute__((ext_vector_type(4)));

// One block = one contiguous 32 KB chunk of the flat [B,T,D] tensor
// (= 32 consecutive t-rows of one batch). Fill-like linear address streams.
__global__ __launch_bounds__(256) void gre_stream_fused(
    const f32x4* __restrict__ x4,
    const float* __restrict__ emb,
    const float* __restrict__ mu,
    const float* __restrict__ sigma,
    f32x4* __restrict__ o4)
{
    const int tid = threadIdx.x;
    const size_t base = (size_t)blockIdx.x * CHUNK4 + tid;

    // Phase 1: issue all 8 x loads immediately (contiguous 32 KB block span)
    f32x4 v[JPT];
#pragma unroll
    for (int j = 0; j < JPT; ++j)
        v[j] = x4[base + (size_t)j * 256];

    // Cooperative softmax weights for this block's 32 rows -> LDS.
    // Row r handled (redundantly) by the 8 threads with tid>>3 == r.
    __shared__ float wsm[ROWS_PB][KK];
    {
        const int r = tid >> 3;                       // 0..31
        const int t = ((blockIdx.x * ROWS_PB) & (T_TOTAL - 1)) + r;
        float lp[KK];
        float mx = -INFINITY;
#pragma unroll
        for (int k = 0; k < KK; ++k) {
            const float mk = mu[k];
            const float sk = sigma[k];
            const float a  = (float)t - mk;
            const float val = -(a * a) / (2.0f * sk + 1e-8f)
                              - 0.5f * __logf(fabsf(sk) + 1e-8f);
            lp[k] = val;
            mx = fmaxf(mx, val);
        }
        float s = 0.0f;
#pragma unroll
        for (int k = 0; k < KK; ++k) { lp[k] = __expf(lp[k] - mx); s += lp[k]; }
        const float inv = 1.0f / s;
        // 8 threads per row write identical values (harmless); k split 8+2
        const int k0 = tid & 7;
        wsm[r][k0] = lp[k0] * inv;
        if (k0 < 2) wsm[r][8 + k0] = lp[8 + k0] * inv;
    }

    // emb columns for this thread's column c -> registers (tiny, L1/L2-hot)
    const int c = tid & 63;
    const f32x4* __restrict__ emb4 = (const f32x4*)emb;
    f32x4 e[KK];
#pragma unroll
    for (int k = 0; k < KK; ++k)
        e[k] = emb4[k * D4 + c];

    __syncthreads();  // wsm ready

    // Phase 2: pe from LDS-broadcast weights + register emb, add, nt store.
    // Row for element j: (tid>>6) + 4*j  (same for all lanes of a wave -> broadcast)
#pragma unroll
    for (int j = 0; j < JPT; ++j) {
        const int r = (tid >> 6) + 4 * j;
        f32x4 pe = (f32x4){0.f, 0.f, 0.f, 0.f};
#pragma unroll
        for (int k = 0; k < KK; ++k)
            pe += wsm[r][k] * e[k];
        f32x4 res = v[j] + pe;
        __builtin_nontemporal_store(res, &o4[base + (size_t)j * 256]);
    }
}

extern "C" void kernel_launch(void* const* d_in, const int* in_sizes, int n_in,
                              void* d_out, int out_size, void* d_ws, size_t ws_size,
                              hipStream_t stream) {
    const float* x     = (const float*)d_in[0];
    const float* emb   = (const float*)d_in[1];
    const float* mu    = (const float*)d_in[2];
    const float* sigma = (const float*)d_in[3];
    float* out         = (float*)d_out;

    const int blocks = (int)(TOT4 / CHUNK4);  // 8192
    gre_stream_fused<<<blocks, 256, 0, stream>>>(
        (const f32x4*)x, emb, mu, sigma, (f32x4*)out);
}